// Round 1
// baseline (1031.426 us; speedup 1.0000x reference)
//
#include <hip/hip_runtime.h>

// ---------------- degree / dinv ----------------

__global__ void init_deg_kernel(int* __restrict__ deg, int n) {
    int i = blockIdx.x * blockDim.x + threadIdx.x;
    if (i < n) deg[i] = 1;  // self-loop contributes 1 to every node's degree
}

__global__ void count_deg_kernel(const int* __restrict__ dst, int* deg, int E) {
    int e = blockIdx.x * blockDim.x + threadIdx.x;
    if (e < E) atomicAdd(&deg[dst[e]], 1);
}

__global__ void dinv_kernel(const int* __restrict__ deg, float* __restrict__ dinv, int n) {
    int i = blockIdx.x * blockDim.x + threadIdx.x;
    if (i < n) dinv[i] = rsqrtf((float)deg[i]);
}

// ---------------- exclusive scan of indeg (deg-1) -> row_start, cursor ----------------
// Single block, 1024 threads (16 waves). ~100 iterations over 100k elements.

__global__ void scan_kernel(const int* __restrict__ deg, int* __restrict__ row_start,
                            int* __restrict__ cursor, int n) {
    __shared__ int wave_tot[16];
    __shared__ int s_carry;
    int tid  = threadIdx.x;
    int lane = tid & 63;
    int wid  = tid >> 6;
    if (tid == 0) s_carry = 0;
    __syncthreads();
    for (int base = 0; base < n; base += 1024) {
        int i = base + tid;
        int v = (i < n) ? (deg[i] - 1) : 0;
        // inclusive wave scan
        int inc = v;
        #pragma unroll
        for (int off = 1; off < 64; off <<= 1) {
            int t = __shfl_up(inc, off);
            if (lane >= off) inc += t;
        }
        if (lane == 63) wave_tot[wid] = inc;
        __syncthreads();
        if (tid == 0) {
            int run = s_carry;
            #pragma unroll
            for (int w = 0; w < 16; ++w) { int t = wave_tot[w]; wave_tot[w] = run; run += t; }
            s_carry = run;
        }
        __syncthreads();
        if (i < n) {
            int excl = wave_tot[wid] + (inc - v);
            row_start[i] = excl;
            cursor[i]    = excl;
        }
        __syncthreads();  // protect wave_tot before next iteration overwrites it
    }
    if (tid == 0) row_start[n] = s_carry;  // == E
}

// ---------------- CSR fill ----------------

__global__ void fill_csr_kernel(const int* __restrict__ src, const int* __restrict__ dst,
                                int* cursor, int* __restrict__ csr_src, int E) {
    int e = blockIdx.x * blockDim.x + threadIdx.x;
    if (e < E) {
        int pos = atomicAdd(&cursor[dst[e]], 1);
        csr_src[pos] = src[e];
    }
}

// ---------------- per-node linear: g[i] = dinv[i] * (in[i] @ W) ----------------

template <int FIN, int FOUT>
__global__ void linear_kernel(const float* __restrict__ in, const float* __restrict__ W,
                              const float* __restrict__ dinv, float* __restrict__ g, int n) {
    __shared__ float sW[FIN * FOUT];
    for (int i = threadIdx.x; i < FIN * FOUT; i += blockDim.x) sW[i] = W[i];
    __syncthreads();
    int node = blockIdx.x * blockDim.x + threadIdx.x;
    if (node >= n) return;
    float xi[FIN];
    #pragma unroll
    for (int k = 0; k < FIN; ++k) xi[k] = in[node * FIN + k];
    float s = dinv[node];
    #pragma unroll
    for (int f = 0; f < FOUT; ++f) {
        float acc = 0.f;
        #pragma unroll
        for (int k = 0; k < FIN; ++k) acc = fmaf(xi[k], sW[k * FOUT + f], acc);
        g[node * FOUT + f] = acc * s;
    }
}

// ---------------- gather-aggregate: out[d] = dinv[d]*(sum_{s in N(d)} g[s] + g[d]) + b ----------------
// One wave per node; 64/FOUT neighbors processed per iteration; coalesced g-row reads.

template <int FOUT, bool RELU>
__global__ void aggregate_kernel(const float* __restrict__ g, const int* __restrict__ row_start,
                                 const int* __restrict__ csr_src, const float* __restrict__ dinv,
                                 const float* __restrict__ bias, float* __restrict__ out, int n) {
    constexpr int NPG = 64 / FOUT;  // neighbors per wave-iteration
    int lane = threadIdx.x & 63;
    int wid  = threadIdx.x >> 6;
    int node = blockIdx.x * (blockDim.x >> 6) + wid;
    if (node >= n) return;
    int f   = lane % FOUT;
    int grp = lane / FOUT;
    int beg = row_start[node];
    int end = row_start[node + 1];
    float acc = 0.f;
    for (int p = beg + grp; p < end; p += NPG) {
        int s = csr_src[p];
        acc += g[s * FOUT + f];
    }
    // reduce partial sums across neighbor groups (lanes with same f)
    #pragma unroll
    for (int off = FOUT; off < 64; off <<= 1) acc += __shfl_xor(acc, off);
    float val = dinv[node] * (acc + g[node * FOUT + f]) + bias[f];
    if (RELU) val = fmaxf(val, 0.f);
    if (grp == 0) out[node * FOUT + f] = val;
}

// ---------------- launch ----------------

extern "C" void kernel_launch(void* const* d_in, const int* in_sizes, int n_in,
                              void* d_out, int out_size, void* d_ws, size_t ws_size,
                              hipStream_t stream) {
    const float* x  = (const float*)d_in[0];
    const int*   ei = (const int*)d_in[1];
    const float* W1 = (const float*)d_in[2];
    const float* b1 = (const float*)d_in[3];
    const float* W2 = (const float*)d_in[4];
    const float* b2 = (const float*)d_in[5];
    const float* W3 = (const float*)d_in[6];
    const float* b3 = (const float*)d_in[7];
    float* out = (float*)d_out;

    const int n = in_sizes[0] / 11;   // 100000
    const int E = in_sizes[1] / 2;    // 3200000
    const int* src = ei;
    const int* dst = ei + E;

    char* ws = (char*)d_ws;
    size_t off = 0;
    auto alloc = [&](size_t bytes) {
        void* p = ws + off;
        off = (off + bytes + 255) & ~(size_t)255;
        return p;
    };
    int*   deg       = (int*)  alloc((size_t)n * 4);
    float* dinv      = (float*)alloc((size_t)n * 4);
    int*   row_start = (int*)  alloc((size_t)(n + 1) * 4);
    int*   cursor    = (int*)  alloc((size_t)n * 4);
    int*   csr_src   = (int*)  alloc((size_t)E * 4);
    float* g         = (float*)alloc((size_t)n * 64 * 4);
    float* h1        = (float*)alloc((size_t)n * 16 * 4);
    float* h2        = (float*)alloc((size_t)n * 32 * 4);
    (void)ws_size;

    const int B = 256;
    int gn = (n + B - 1) / B;
    int gE = (E + B - 1) / B;
    int gagg = (n + 3) / 4;  // 4 waves per 256-thread block, one wave per node

    // graph structure (identical all 3 layers)
    init_deg_kernel<<<gn, B, 0, stream>>>(deg, n);
    count_deg_kernel<<<gE, B, 0, stream>>>(dst, deg, E);
    dinv_kernel<<<gn, B, 0, stream>>>(deg, dinv, n);
    scan_kernel<<<1, 1024, 0, stream>>>(deg, row_start, cursor, n);
    fill_csr_kernel<<<gE, B, 0, stream>>>(src, dst, cursor, csr_src, E);

    // layer 1: 11 -> 16, relu
    linear_kernel<11, 16><<<gn, B, 0, stream>>>(x, W1, dinv, g, n);
    aggregate_kernel<16, true><<<gagg, B, 0, stream>>>(g, row_start, csr_src, dinv, b1, h1, n);

    // layer 2: 16 -> 32, relu
    linear_kernel<16, 32><<<gn, B, 0, stream>>>(h1, W2, dinv, g, n);
    aggregate_kernel<32, true><<<gagg, B, 0, stream>>>(g, row_start, csr_src, dinv, b2, h2, n);

    // layer 3: 32 -> 64, no relu
    linear_kernel<32, 64><<<gn, B, 0, stream>>>(h2, W3, dinv, g, n);
    aggregate_kernel<64, false><<<gagg, B, 0, stream>>>(g, row_start, csr_src, dinv, b3, out, n);
}

// Round 2
// 536.321 us; speedup vs baseline: 1.9231x; 1.9231x over previous
//
#include <hip/hip_runtime.h>

// ---------------- zero counters ----------------

__global__ void zero_kernel(int* __restrict__ p, int n) {
    int i = blockIdx.x * blockDim.x + threadIdx.x;
    if (i < n) p[i] = 0;
}

// ---------------- pass 1: indegree count + per-edge rank (4 edges/thread) ----------------

__global__ void count_rank_kernel(const int* __restrict__ dst, int* cnt,
                                  int* __restrict__ rank, int E) {
    int e0 = (blockIdx.x * blockDim.x + threadIdx.x) * 4;
    if (e0 + 3 < E) {
        int4 d = *reinterpret_cast<const int4*>(dst + e0);
        int4 r;
        r.x = atomicAdd(&cnt[d.x], 1);
        r.y = atomicAdd(&cnt[d.y], 1);
        r.z = atomicAdd(&cnt[d.z], 1);
        r.w = atomicAdd(&cnt[d.w], 1);
        *reinterpret_cast<int4*>(rank + e0) = r;
    } else {
        for (int e = e0; e < E; ++e) rank[e] = atomicAdd(&cnt[dst[e]], 1);
    }
}

// ---------------- dinv = rsqrt(indeg + 1)  (self-loop) ----------------

__global__ void dinv_kernel(const int* __restrict__ cnt, float* __restrict__ dinv, int n) {
    int i = blockIdx.x * blockDim.x + threadIdx.x;
    if (i < n) dinv[i] = rsqrtf((float)(cnt[i] + 1));
}

// ---------------- exclusive scan of indeg -> row_start ----------------
// Single block, 1024 threads (16 waves). ~100 iterations over 100k elements.

__global__ void scan_kernel(const int* __restrict__ cnt, int* __restrict__ row_start, int n) {
    __shared__ int wave_tot[16];
    __shared__ int s_carry;
    int tid  = threadIdx.x;
    int lane = tid & 63;
    int wid  = tid >> 6;
    if (tid == 0) s_carry = 0;
    __syncthreads();
    for (int base = 0; base < n; base += 1024) {
        int i = base + tid;
        int v = (i < n) ? cnt[i] : 0;
        int inc = v;
        #pragma unroll
        for (int off = 1; off < 64; off <<= 1) {
            int t = __shfl_up(inc, off);
            if (lane >= off) inc += t;
        }
        if (lane == 63) wave_tot[wid] = inc;
        __syncthreads();
        if (tid == 0) {
            int run = s_carry;
            #pragma unroll
            for (int w = 0; w < 16; ++w) { int t = wave_tot[w]; wave_tot[w] = run; run += t; }
            s_carry = run;
        }
        __syncthreads();
        if (i < n) row_start[i] = wave_tot[wid] + (inc - v);
        __syncthreads();
    }
    if (tid == 0) row_start[n] = s_carry;  // == E
}

// ---------------- pass 2: CSR fill, no atomics (4 edges/thread) ----------------

__global__ void fill_csr_kernel(const int* __restrict__ src, const int* __restrict__ dst,
                                const int* __restrict__ rank, const int* __restrict__ row_start,
                                int* __restrict__ csr_src, int E) {
    int e0 = (blockIdx.x * blockDim.x + threadIdx.x) * 4;
    if (e0 + 3 < E) {
        int4 s = *reinterpret_cast<const int4*>(src + e0);
        int4 d = *reinterpret_cast<const int4*>(dst + e0);
        int4 r = *reinterpret_cast<const int4*>(rank + e0);
        int p0 = row_start[d.x] + r.x;
        int p1 = row_start[d.y] + r.y;
        int p2 = row_start[d.z] + r.z;
        int p3 = row_start[d.w] + r.w;
        csr_src[p0] = s.x;
        csr_src[p1] = s.y;
        csr_src[p2] = s.z;
        csr_src[p3] = s.w;
    } else {
        for (int e = e0; e < E; ++e) csr_src[row_start[dst[e]] + rank[e]] = src[e];
    }
}

// ---------------- per-node linear: g[i] = dinv[i] * (in[i] @ W) ----------------

template <int FIN, int FOUT>
__global__ void linear_kernel(const float* __restrict__ in, const float* __restrict__ W,
                              const float* __restrict__ dinv, float* __restrict__ g, int n) {
    __shared__ float sW[FIN * FOUT];
    for (int i = threadIdx.x; i < FIN * FOUT; i += blockDim.x) sW[i] = W[i];
    __syncthreads();
    int node = blockIdx.x * blockDim.x + threadIdx.x;
    if (node >= n) return;
    float xi[FIN];
    #pragma unroll
    for (int k = 0; k < FIN; ++k) xi[k] = in[node * FIN + k];
    float s = dinv[node];
    #pragma unroll
    for (int f = 0; f < FOUT; ++f) {
        float acc = 0.f;
        #pragma unroll
        for (int k = 0; k < FIN; ++k) acc = fmaf(xi[k], sW[k * FOUT + f], acc);
        g[node * FOUT + f] = acc * s;
    }
}

// ---------------- gather-aggregate, U-way unrolled for memory-level parallelism ----------------
// out[d] = dinv[d]*(sum_{s in N(d)} g[s] + g[d]) + b
// One wave per node; 64/FOUT neighbors per base iteration; U independent batches in flight.

template <int FOUT, bool RELU, int U>
__global__ void aggregate_kernel(const float* __restrict__ g, const int* __restrict__ row_start,
                                 const int* __restrict__ csr_src, const float* __restrict__ dinv,
                                 const float* __restrict__ bias, float* __restrict__ out, int n) {
    constexpr int NPG = 64 / FOUT;  // neighbors per wave-iteration (per unroll step)
    int lane = threadIdx.x & 63;
    int wid  = threadIdx.x >> 6;
    int node = blockIdx.x * (blockDim.x >> 6) + wid;
    if (node >= n) return;
    int f   = lane % FOUT;
    int grp = lane / FOUT;
    int beg = row_start[node];
    int end = row_start[node + 1];
    float acc = 0.f;
    int p = beg + grp;
    // main: U*NPG neighbors per iteration, U independent index+gather loads in flight
    for (; p + (U - 1) * NPG < end; p += U * NPG) {
        int   s[U];
        float v[U];
        #pragma unroll
        for (int u = 0; u < U; ++u) s[u] = csr_src[p + u * NPG];
        #pragma unroll
        for (int u = 0; u < U; ++u) v[u] = g[(size_t)s[u] * FOUT + f];
        #pragma unroll
        for (int u = 0; u < U; ++u) acc += v[u];
    }
    for (; p < end; p += NPG) acc += g[(size_t)csr_src[p] * FOUT + f];
    // reduce partial sums across neighbor groups (lanes with same f)
    #pragma unroll
    for (int off = FOUT; off < 64; off <<= 1) acc += __shfl_xor(acc, off);
    float val = dinv[node] * (acc + g[node * FOUT + f]) + bias[f];
    if (RELU) val = fmaxf(val, 0.f);
    if (grp == 0) out[node * FOUT + f] = val;
}

// ---------------- launch ----------------

extern "C" void kernel_launch(void* const* d_in, const int* in_sizes, int n_in,
                              void* d_out, int out_size, void* d_ws, size_t ws_size,
                              hipStream_t stream) {
    const float* x  = (const float*)d_in[0];
    const int*   ei = (const int*)d_in[1];
    const float* W1 = (const float*)d_in[2];
    const float* b1 = (const float*)d_in[3];
    const float* W2 = (const float*)d_in[4];
    const float* b2 = (const float*)d_in[5];
    const float* W3 = (const float*)d_in[6];
    const float* b3 = (const float*)d_in[7];
    float* out = (float*)d_out;

    const int n = in_sizes[0] / 11;   // 100000
    const int E = in_sizes[1] / 2;    // 3200000
    const int* src = ei;
    const int* dst = ei + E;

    char* ws = (char*)d_ws;
    size_t off = 0;
    auto alloc = [&](size_t bytes) {
        void* p = ws + off;
        off = (off + bytes + 255) & ~(size_t)255;
        return p;
    };
    int*   cnt       = (int*)  alloc((size_t)n * 4);
    float* dinv      = (float*)alloc((size_t)n * 4);
    int*   row_start = (int*)  alloc((size_t)(n + 1) * 4);
    int*   rank      = (int*)  alloc((size_t)E * 4);
    int*   csr_src   = (int*)  alloc((size_t)E * 4);
    float* g         = (float*)alloc((size_t)n * 64 * 4);
    float* h1        = (float*)alloc((size_t)n * 16 * 4);
    float* h2        = (float*)alloc((size_t)n * 32 * 4);
    (void)ws_size;

    const int B = 256;
    int gn  = (n + B - 1) / B;
    int gE4 = (E / 4 + B) / B;        // 4 edges per thread (covers tail)
    int gagg = (n + 3) / 4;           // 4 waves per 256-thread block, one wave per node

    // graph structure (identical all 3 layers)
    zero_kernel<<<gn, B, 0, stream>>>(cnt, n);
    count_rank_kernel<<<gE4, B, 0, stream>>>(dst, cnt, rank, E);
    dinv_kernel<<<gn, B, 0, stream>>>(cnt, dinv, n);
    scan_kernel<<<1, 1024, 0, stream>>>(cnt, row_start, n);
    fill_csr_kernel<<<gE4, B, 0, stream>>>(src, dst, rank, row_start, csr_src, E);

    // layer 1: 11 -> 16, relu
    linear_kernel<11, 16><<<gn, B, 0, stream>>>(x, W1, dinv, g, n);
    aggregate_kernel<16, true, 4><<<gagg, B, 0, stream>>>(g, row_start, csr_src, dinv, b1, h1, n);

    // layer 2: 16 -> 32, relu
    linear_kernel<16, 32><<<gn, B, 0, stream>>>(h1, W2, dinv, g, n);
    aggregate_kernel<32, true, 4><<<gagg, B, 0, stream>>>(g, row_start, csr_src, dinv, b2, h2, n);

    // layer 3: 32 -> 64, no relu
    linear_kernel<32, 64><<<gn, B, 0, stream>>>(h2, W3, dinv, g, n);
    aggregate_kernel<64, false, 8><<<gagg, B, 0, stream>>>(g, row_start, csr_src, dinv, b3, out, n);
}

// Round 3
// 467.651 us; speedup vs baseline: 2.2055x; 1.1468x over previous
//
#include <hip/hip_runtime.h>

#define NREP 8  // counter replicas (contention / NREP)

// ---------------- zero counters ----------------

__global__ void zero_kernel(int* __restrict__ p, int n) {
    int i = blockIdx.x * blockDim.x + threadIdx.x;
    if (i < n) p[i] = 0;
}

// ---------------- pass 1: replicated indegree count + per-edge local rank (8 edges/thread) ---

__global__ void count_rank_kernel(const int* __restrict__ dst, int* cnt8,
                                  int* __restrict__ rank, int E, int n) {
    int t = blockIdx.x * blockDim.x + threadIdx.x;
    int e0 = t * 8;
    int* cnt = cnt8 + (size_t)(blockIdx.x & (NREP - 1)) * n;
    if (e0 + 7 < E) {
        int4 d0 = *reinterpret_cast<const int4*>(dst + e0);
        int4 d1 = *reinterpret_cast<const int4*>(dst + e0 + 4);
        int4 r0, r1;
        r0.x = atomicAdd(&cnt[d0.x], 1);
        r0.y = atomicAdd(&cnt[d0.y], 1);
        r0.z = atomicAdd(&cnt[d0.z], 1);
        r0.w = atomicAdd(&cnt[d0.w], 1);
        r1.x = atomicAdd(&cnt[d1.x], 1);
        r1.y = atomicAdd(&cnt[d1.y], 1);
        r1.z = atomicAdd(&cnt[d1.z], 1);
        r1.w = atomicAdd(&cnt[d1.w], 1);
        *reinterpret_cast<int4*>(rank + e0)     = r0;
        *reinterpret_cast<int4*>(rank + e0 + 4) = r1;
    } else {
        for (int e = e0; e < E; ++e) rank[e] = atomicAdd(&cnt[dst[e]], 1);
    }
}

// ---------------- pass 2: per-node replica prefix -> bases; indeg; dinv ----------------

__global__ void reduce_replicas_kernel(int* cnt8, int* __restrict__ indeg,
                                       float* __restrict__ dinv, int n) {
    int i = blockIdx.x * blockDim.x + threadIdx.x;
    if (i >= n) return;
    int s = 0;
    #pragma unroll
    for (int r = 0; r < NREP; ++r) {
        int t = cnt8[(size_t)r * n + i];
        cnt8[(size_t)r * n + i] = s;   // exclusive base within node i
        s += t;
    }
    indeg[i] = s;
    dinv[i]  = rsqrtf((float)(s + 1));  // self-loop
}

// ---------------- 3-phase exclusive scan of indeg -> row_start ----------------
// phase A: per-block (1024-chunk) local exclusive scan + block totals

__global__ void scan_block_kernel(const int* __restrict__ indeg, int* __restrict__ row_start,
                                  int* __restrict__ partial, int n) {
    __shared__ int wtot[16];
    int tid  = threadIdx.x;
    int lane = tid & 63;
    int wid  = tid >> 6;
    int i = blockIdx.x * 1024 + tid;
    int v = (i < n) ? indeg[i] : 0;
    int inc = v;
    #pragma unroll
    for (int off = 1; off < 64; off <<= 1) {
        int t = __shfl_up(inc, off);
        if (lane >= off) inc += t;
    }
    if (lane == 63) wtot[wid] = inc;
    __syncthreads();
    if (tid == 0) {
        int run = 0;
        #pragma unroll
        for (int w = 0; w < 16; ++w) { int t = wtot[w]; wtot[w] = run; run += t; }
        partial[blockIdx.x] = run;
    }
    __syncthreads();
    if (i < n) row_start[i] = wtot[wid] + (inc - v);
}

// phase B: single-wave scan of block partials (in place), nb <= 128

__global__ void scan_partials_kernel(int* partial, int nb) {
    int t = threadIdx.x;  // 64 threads
    int i0 = 2 * t, i1 = 2 * t + 1;
    int v0 = (i0 < nb) ? partial[i0] : 0;
    int v1 = (i1 < nb) ? partial[i1] : 0;
    int s = v0 + v1;
    int inc = s;
    #pragma unroll
    for (int off = 1; off < 64; off <<= 1) {
        int u = __shfl_up(inc, off);
        if (t >= off) inc += u;
    }
    int excl = inc - s;
    if (i0 < nb) partial[i0] = excl;
    if (i1 < nb) partial[i1] = excl + v0;
}

// phase C: add block base; set row_start[n] = E

__global__ void add_base_kernel(int* row_start, const int* __restrict__ partial, int n, int E) {
    int i = blockIdx.x * blockDim.x + threadIdx.x;
    if (i < n) row_start[i] += partial[i >> 10];
    if (i == n) row_start[n] = E;
}

// ---------------- fold row_start into replica bases: cnt8[r][i] += row_start[i] -------------

__global__ void add_rowstart_kernel(int* cnt8, const int* __restrict__ row_start, int n) {
    int i = blockIdx.x * blockDim.x + threadIdx.x;
    if (i >= n) return;
    int rs = row_start[i];
    #pragma unroll
    for (int r = 0; r < NREP; ++r) cnt8[(size_t)r * n + i] += rs;
}

// ---------------- pass 3: CSR fill, no atomics, one gather per edge (8 edges/thread) --------

__global__ void fill_csr_kernel(const int* __restrict__ src, const int* __restrict__ dst,
                                const int* __restrict__ rank, const int* __restrict__ cnt8,
                                int* __restrict__ csr_src, int E, int n) {
    int t = blockIdx.x * blockDim.x + threadIdx.x;
    int e0 = t * 8;
    const int* base = cnt8 + (size_t)(blockIdx.x & (NREP - 1)) * n;  // same mapping as count pass
    if (e0 + 7 < E) {
        int4 s0 = *reinterpret_cast<const int4*>(src + e0);
        int4 s1 = *reinterpret_cast<const int4*>(src + e0 + 4);
        int4 d0 = *reinterpret_cast<const int4*>(dst + e0);
        int4 d1 = *reinterpret_cast<const int4*>(dst + e0 + 4);
        int4 r0 = *reinterpret_cast<const int4*>(rank + e0);
        int4 r1 = *reinterpret_cast<const int4*>(rank + e0 + 4);
        int p0 = base[d0.x] + r0.x;
        int p1 = base[d0.y] + r0.y;
        int p2 = base[d0.z] + r0.z;
        int p3 = base[d0.w] + r0.w;
        int p4 = base[d1.x] + r1.x;
        int p5 = base[d1.y] + r1.y;
        int p6 = base[d1.z] + r1.z;
        int p7 = base[d1.w] + r1.w;
        csr_src[p0] = s0.x;
        csr_src[p1] = s0.y;
        csr_src[p2] = s0.z;
        csr_src[p3] = s0.w;
        csr_src[p4] = s1.x;
        csr_src[p5] = s1.y;
        csr_src[p6] = s1.z;
        csr_src[p7] = s1.w;
    } else {
        for (int e = e0; e < E; ++e) csr_src[base[dst[e]] + rank[e]] = src[e];
    }
}

// ---------------- per-node linear: g[i] = dinv[i] * (in[i] @ W) ----------------

template <int FIN, int FOUT>
__global__ void linear_kernel(const float* __restrict__ in, const float* __restrict__ W,
                              const float* __restrict__ dinv, float* __restrict__ g, int n) {
    __shared__ float sW[FIN * FOUT];
    for (int i = threadIdx.x; i < FIN * FOUT; i += blockDim.x) sW[i] = W[i];
    __syncthreads();
    int node = blockIdx.x * blockDim.x + threadIdx.x;
    if (node >= n) return;
    float xi[FIN];
    #pragma unroll
    for (int k = 0; k < FIN; ++k) xi[k] = in[node * FIN + k];
    float s = dinv[node];
    #pragma unroll
    for (int f = 0; f < FOUT; ++f) {
        float acc = 0.f;
        #pragma unroll
        for (int k = 0; k < FIN; ++k) acc = fmaf(xi[k], sW[k * FOUT + f], acc);
        g[node * FOUT + f] = acc * s;
    }
}

// ---------------- gather-aggregate, U-way unrolled for memory-level parallelism ----------------
// out[d] = dinv[d]*(sum_{s in N(d)} g[s] + g[d]) + b

template <int FOUT, bool RELU, int U>
__global__ void aggregate_kernel(const float* __restrict__ g, const int* __restrict__ row_start,
                                 const int* __restrict__ csr_src, const float* __restrict__ dinv,
                                 const float* __restrict__ bias, float* __restrict__ out, int n) {
    constexpr int NPG = 64 / FOUT;  // neighbors per wave-iteration (per unroll step)
    int lane = threadIdx.x & 63;
    int wid  = threadIdx.x >> 6;
    int node = blockIdx.x * (blockDim.x >> 6) + wid;
    if (node >= n) return;
    int f   = lane % FOUT;
    int grp = lane / FOUT;
    int beg = row_start[node];
    int end = row_start[node + 1];
    float acc = 0.f;
    int p = beg + grp;
    for (; p + (U - 1) * NPG < end; p += U * NPG) {
        int   s[U];
        float v[U];
        #pragma unroll
        for (int u = 0; u < U; ++u) s[u] = csr_src[p + u * NPG];
        #pragma unroll
        for (int u = 0; u < U; ++u) v[u] = g[(size_t)s[u] * FOUT + f];
        #pragma unroll
        for (int u = 0; u < U; ++u) acc += v[u];
    }
    for (; p < end; p += NPG) acc += g[(size_t)csr_src[p] * FOUT + f];
    #pragma unroll
    for (int off = FOUT; off < 64; off <<= 1) acc += __shfl_xor(acc, off);
    float val = dinv[node] * (acc + g[node * FOUT + f]) + bias[f];
    if (RELU) val = fmaxf(val, 0.f);
    if (grp == 0) out[node * FOUT + f] = val;
}

// ---------------- launch ----------------

extern "C" void kernel_launch(void* const* d_in, const int* in_sizes, int n_in,
                              void* d_out, int out_size, void* d_ws, size_t ws_size,
                              hipStream_t stream) {
    const float* x  = (const float*)d_in[0];
    const int*   ei = (const int*)d_in[1];
    const float* W1 = (const float*)d_in[2];
    const float* b1 = (const float*)d_in[3];
    const float* W2 = (const float*)d_in[4];
    const float* b2 = (const float*)d_in[5];
    const float* W3 = (const float*)d_in[6];
    const float* b3 = (const float*)d_in[7];
    float* out = (float*)d_out;

    const int n = in_sizes[0] / 11;   // 100000
    const int E = in_sizes[1] / 2;    // 3200000
    const int* src = ei;
    const int* dst = ei + E;

    char* ws = (char*)d_ws;
    size_t off = 0;
    auto alloc = [&](size_t bytes) {
        void* p = ws + off;
        off = (off + bytes + 255) & ~(size_t)255;
        return p;
    };
    int*   cnt8      = (int*)  alloc((size_t)NREP * n * 4);
    int*   indeg     = (int*)  alloc((size_t)n * 4);
    float* dinv      = (float*)alloc((size_t)n * 4);
    int*   row_start = (int*)  alloc((size_t)(n + 1) * 4);
    int*   partial   = (int*)  alloc((size_t)128 * 4);
    int*   rank      = (int*)  alloc((size_t)E * 4);
    int*   csr_src   = (int*)  alloc((size_t)E * 4);
    float* g         = (float*)alloc((size_t)n * 64 * 4);
    float* h1        = (float*)alloc((size_t)n * 16 * 4);
    float* h2        = (float*)alloc((size_t)n * 32 * 4);
    (void)ws_size;

    const int B = 256;
    int gn   = (n + B - 1) / B;
    int gn1  = (n + 1 + B - 1) / B;           // covers row_start[n]
    int g8n  = (NREP * n + B - 1) / B;
    int gE8  = (E / 8 + B) / B;               // 8 edges per thread (covers tail)
    int nb   = (n + 1023) / 1024;             // scan blocks (98 for n=100k)
    int gagg = (n + 3) / 4;                   // one wave per node

    // graph structure
    zero_kernel<<<g8n, B, 0, stream>>>(cnt8, NREP * n);
    count_rank_kernel<<<gE8, B, 0, stream>>>(dst, cnt8, rank, E, n);
    reduce_replicas_kernel<<<gn, B, 0, stream>>>(cnt8, indeg, dinv, n);
    scan_block_kernel<<<nb, 1024, 0, stream>>>(indeg, row_start, partial, n);
    scan_partials_kernel<<<1, 64, 0, stream>>>(partial, nb);
    add_base_kernel<<<gn1, B, 0, stream>>>(row_start, partial, n, E);
    add_rowstart_kernel<<<gn, B, 0, stream>>>(cnt8, row_start, n);
    fill_csr_kernel<<<gE8, B, 0, stream>>>(src, dst, rank, cnt8, csr_src, E, n);

    // layer 1: 11 -> 16, relu
    linear_kernel<11, 16><<<gn, B, 0, stream>>>(x, W1, dinv, g, n);
    aggregate_kernel<16, true, 4><<<gagg, B, 0, stream>>>(g, row_start, csr_src, dinv, b1, h1, n);

    // layer 2: 16 -> 32, relu
    linear_kernel<16, 32><<<gn, B, 0, stream>>>(h1, W2, dinv, g, n);
    aggregate_kernel<32, true, 4><<<gagg, B, 0, stream>>>(g, row_start, csr_src, dinv, b2, h2, n);

    // layer 3: 32 -> 64, no relu
    linear_kernel<32, 64><<<gn, B, 0, stream>>>(h2, W3, dinv, g, n);
    aggregate_kernel<64, false, 8><<<gagg, B, 0, stream>>>(g, row_start, csr_src, dinv, b3, out, n);
}

// Round 4
// 446.559 us; speedup vs baseline: 2.3097x; 1.0472x over previous
//
#include <hip/hip_runtime.h>

// ---------------- zero ----------------

__global__ void zero_kernel(int* __restrict__ p, int n) {
    int i = blockIdx.x * blockDim.x + threadIdx.x;
    if (i < n) p[i] = 0;
}

// ---------------- pass 1: indegree count + per-edge rank (8 edges/thread) ----------------

__global__ void count_rank_kernel(const int* __restrict__ dst, int* cnt,
                                  int* __restrict__ rank, int E) {
    int t = blockIdx.x * blockDim.x + threadIdx.x;
    int e0 = t * 8;
    if (e0 + 7 < E) {
        int4 d0 = *reinterpret_cast<const int4*>(dst + e0);
        int4 d1 = *reinterpret_cast<const int4*>(dst + e0 + 4);
        int4 r0, r1;
        r0.x = atomicAdd(&cnt[d0.x], 1);
        r0.y = atomicAdd(&cnt[d0.y], 1);
        r0.z = atomicAdd(&cnt[d0.z], 1);
        r0.w = atomicAdd(&cnt[d0.w], 1);
        r1.x = atomicAdd(&cnt[d1.x], 1);
        r1.y = atomicAdd(&cnt[d1.y], 1);
        r1.z = atomicAdd(&cnt[d1.z], 1);
        r1.w = atomicAdd(&cnt[d1.w], 1);
        *reinterpret_cast<int4*>(rank + e0)     = r0;
        *reinterpret_cast<int4*>(rank + e0 + 4) = r1;
    } else {
        for (int e = e0; e < E; ++e) rank[e] = atomicAdd(&cnt[dst[e]], 1);
    }
}

// ---------------- dinv = rsqrt(indeg + 1) ----------------

__global__ void dinv_kernel(const int* __restrict__ cnt, float* __restrict__ dinv, int n) {
    int i = blockIdx.x * blockDim.x + threadIdx.x;
    if (i < n) dinv[i] = rsqrtf((float)(cnt[i] + 1));
}

// ---------------- 3-phase exclusive scan of indeg -> row_start ----------------

__global__ void scan_block_kernel(const int* __restrict__ indeg, int* __restrict__ row_start,
                                  int* __restrict__ partial, int n) {
    __shared__ int wtot[16];
    int tid  = threadIdx.x;
    int lane = tid & 63;
    int wid  = tid >> 6;
    int i = blockIdx.x * 1024 + tid;
    int v = (i < n) ? indeg[i] : 0;
    int inc = v;
    #pragma unroll
    for (int off = 1; off < 64; off <<= 1) {
        int t = __shfl_up(inc, off);
        if (lane >= off) inc += t;
    }
    if (lane == 63) wtot[wid] = inc;
    __syncthreads();
    if (tid == 0) {
        int run = 0;
        #pragma unroll
        for (int w = 0; w < 16; ++w) { int t = wtot[w]; wtot[w] = run; run += t; }
        partial[blockIdx.x] = run;
    }
    __syncthreads();
    if (i < n) row_start[i] = wtot[wid] + (inc - v);
}

__global__ void scan_partials_kernel(int* partial, int nb) {
    int t = threadIdx.x;  // 64 threads
    int i0 = 2 * t, i1 = 2 * t + 1;
    int v0 = (i0 < nb) ? partial[i0] : 0;
    int v1 = (i1 < nb) ? partial[i1] : 0;
    int s = v0 + v1;
    int inc = s;
    #pragma unroll
    for (int off = 1; off < 64; off <<= 1) {
        int u = __shfl_up(inc, off);
        if (t >= off) inc += u;
    }
    int excl = inc - s;
    if (i0 < nb) partial[i0] = excl;
    if (i1 < nb) partial[i1] = excl + v0;
}

__global__ void add_base_kernel(int* row_start, const int* __restrict__ partial, int n, int E) {
    int i = blockIdx.x * blockDim.x + threadIdx.x;
    if (i < n) row_start[i] += partial[i >> 10];
    if (i == n) row_start[n] = E;
}

// ---------------- CSR fill, no atomics, one gather per edge (8 edges/thread) ----------------

__global__ void fill_csr_kernel(const int* __restrict__ src, const int* __restrict__ dst,
                                const int* __restrict__ rank, const int* __restrict__ row_start,
                                int* __restrict__ csr_src, int E) {
    int t = blockIdx.x * blockDim.x + threadIdx.x;
    int e0 = t * 8;
    if (e0 + 7 < E) {
        int4 s0 = *reinterpret_cast<const int4*>(src + e0);
        int4 s1 = *reinterpret_cast<const int4*>(src + e0 + 4);
        int4 d0 = *reinterpret_cast<const int4*>(dst + e0);
        int4 d1 = *reinterpret_cast<const int4*>(dst + e0 + 4);
        int4 r0 = *reinterpret_cast<const int4*>(rank + e0);
        int4 r1 = *reinterpret_cast<const int4*>(rank + e0 + 4);
        csr_src[row_start[d0.x] + r0.x] = s0.x;
        csr_src[row_start[d0.y] + r0.y] = s0.y;
        csr_src[row_start[d0.z] + r0.z] = s0.z;
        csr_src[row_start[d0.w] + r0.w] = s0.w;
        csr_src[row_start[d1.x] + r1.x] = s1.x;
        csr_src[row_start[d1.y] + r1.y] = s1.y;
        csr_src[row_start[d1.z] + r1.z] = s1.z;
        csr_src[row_start[d1.w] + r1.w] = s1.w;
    } else {
        for (int e = e0; e < E; ++e) csr_src[row_start[dst[e]] + rank[e]] = src[e];
    }
}

// ---------------- pad + scale: g0[i][k] = (k<11) ? x[i][k]*dinv[i] : 0  (16-wide) ------------

__global__ void pad_scale_kernel(const float* __restrict__ x, const float* __restrict__ dinv,
                                 float* __restrict__ g, int n) {
    int i = blockIdx.x * blockDim.x + threadIdx.x;
    if (i >= n) return;
    float s = dinv[i];
    float v[16];
    #pragma unroll
    for (int k = 0; k < 11; ++k) v[k] = x[i * 11 + k] * s;
    #pragma unroll
    for (int k = 11; k < 16; ++k) v[k] = 0.f;
    #pragma unroll
    for (int k = 0; k < 16; ++k) g[i * 16 + k] = v[k];
}

// ---------------- gather-aggregate (pre-linear features) ----------------
// pre[d] = dinv[d] * (sum_{s in N(d)} g[s] + g[d]);  g already carries dinv[s].

template <int FOUT, int U>
__global__ void aggregate_kernel(const float* __restrict__ g, const int* __restrict__ row_start,
                                 const int* __restrict__ csr_src, const float* __restrict__ dinv,
                                 float* __restrict__ pre, int n) {
    constexpr int NPG = 64 / FOUT;  // neighbors per wave-iteration (per unroll step)
    int lane = threadIdx.x & 63;
    int wid  = threadIdx.x >> 6;
    int node = blockIdx.x * (blockDim.x >> 6) + wid;
    if (node >= n) return;
    int f   = lane % FOUT;
    int grp = lane / FOUT;
    int beg = row_start[node];
    int end = row_start[node + 1];
    float acc = 0.f;
    int p = beg + grp;
    for (; p + (U - 1) * NPG < end; p += U * NPG) {
        int   s[U];
        float v[U];
        #pragma unroll
        for (int u = 0; u < U; ++u) s[u] = csr_src[p + u * NPG];
        #pragma unroll
        for (int u = 0; u < U; ++u) v[u] = g[(size_t)s[u] * FOUT + f];
        #pragma unroll
        for (int u = 0; u < U; ++u) acc += v[u];
    }
    for (; p < end; p += NPG) acc += g[(size_t)csr_src[p] * FOUT + f];
    #pragma unroll
    for (int off = FOUT; off < 64; off <<= 1) acc += __shfl_xor(acc, off);
    float val = dinv[node] * (acc + g[node * FOUT + f]);
    if (grp == 0) pre[node * FOUT + f] = val;
}

// ---------------- post-agg linear: out = [relu](pre @ W + b) [* dinv] ----------------
// W is FINR x FOUT row-major; LDS-padded to FINP x FOUT (pad rows zeroed).

template <int FINP, int FINR, int FOUT, bool RELU, bool SCALE>
__global__ void linear_kernel(const float* __restrict__ pre, const float* __restrict__ W,
                              const float* __restrict__ bias, const float* __restrict__ dinv,
                              float* __restrict__ out, int n) {
    __shared__ float sW[FINP * FOUT];
    __shared__ float sB[FOUT];
    for (int i = threadIdx.x; i < FINP * FOUT; i += blockDim.x)
        sW[i] = (i < FINR * FOUT) ? W[i] : 0.f;
    for (int i = threadIdx.x; i < FOUT; i += blockDim.x) sB[i] = bias[i];
    __syncthreads();
    int node = blockIdx.x * blockDim.x + threadIdx.x;
    if (node >= n) return;
    float xi[FINP];
    #pragma unroll
    for (int k = 0; k < FINP; ++k) xi[k] = pre[node * FINP + k];
    float s = SCALE ? dinv[node] : 1.f;
    #pragma unroll
    for (int f = 0; f < FOUT; ++f) {
        float acc = sB[f];
        #pragma unroll
        for (int k = 0; k < FINP; ++k) acc = fmaf(xi[k], sW[k * FOUT + f], acc);
        if (RELU) acc = fmaxf(acc, 0.f);
        out[node * FOUT + f] = acc * s;
    }
}

// ---------------- launch ----------------

extern "C" void kernel_launch(void* const* d_in, const int* in_sizes, int n_in,
                              void* d_out, int out_size, void* d_ws, size_t ws_size,
                              hipStream_t stream) {
    const float* x  = (const float*)d_in[0];
    const int*   ei = (const int*)d_in[1];
    const float* W1 = (const float*)d_in[2];
    const float* b1 = (const float*)d_in[3];
    const float* W2 = (const float*)d_in[4];
    const float* b2 = (const float*)d_in[5];
    const float* W3 = (const float*)d_in[6];
    const float* b3 = (const float*)d_in[7];
    float* out = (float*)d_out;

    const int n = in_sizes[0] / 11;   // 100000
    const int E = in_sizes[1] / 2;    // 3200000
    const int* src = ei;
    const int* dst = ei + E;

    char* ws = (char*)d_ws;
    size_t off = 0;
    auto alloc = [&](size_t bytes) {
        void* p = ws + off;
        off = (off + bytes + 255) & ~(size_t)255;
        return p;
    };
    int*   cnt       = (int*)  alloc((size_t)n * 4);
    float* dinv      = (float*)alloc((size_t)n * 4);
    int*   row_start = (int*)  alloc((size_t)(n + 1) * 4);
    int*   partial   = (int*)  alloc((size_t)128 * 4);
    int*   rank      = (int*)  alloc((size_t)E * 4);
    int*   csr_src   = (int*)  alloc((size_t)E * 4);
    float* bufA      = (float*)alloc((size_t)n * 16 * 4);  // g0 / g1
    float* bufB      = (float*)alloc((size_t)n * 16 * 4);  // pre1 / pre2
    float* bufC      = (float*)alloc((size_t)n * 32 * 4);  // g2
    float* bufD      = (float*)alloc((size_t)n * 32 * 4);  // pre3
    (void)ws_size;

    const int B = 256;
    int gn   = (n + B - 1) / B;
    int gn1  = (n + 1 + B - 1) / B;
    int gE8  = (E / 8 + B) / B;
    int nb   = (n + 1023) / 1024;     // 98 scan blocks
    int gagg = (n + 3) / 4;           // one wave per node

    // graph structure
    zero_kernel<<<gn, B, 0, stream>>>(cnt, n);
    count_rank_kernel<<<gE8, B, 0, stream>>>(dst, cnt, rank, E);
    dinv_kernel<<<gn, B, 0, stream>>>(cnt, dinv, n);
    scan_block_kernel<<<nb, 1024, 0, stream>>>(cnt, row_start, partial, n);
    scan_partials_kernel<<<1, 64, 0, stream>>>(partial, nb);
    add_base_kernel<<<gn1, B, 0, stream>>>(row_start, partial, n, E);
    fill_csr_kernel<<<gE8, B, 0, stream>>>(src, dst, rank, row_start, csr_src, E);

    // g0 = pad16(x) * dinv
    pad_scale_kernel<<<gn, B, 0, stream>>>(x, dinv, bufA, n);

    // layer 1: agg on 16-wide (11 used), then 11->16 linear with relu, scale for next layer
    aggregate_kernel<16, 8><<<gagg, B, 0, stream>>>(bufA, row_start, csr_src, dinv, bufB, n);
    linear_kernel<16, 11, 16, true, true><<<gn, B, 0, stream>>>(bufB, W1, b1, dinv, bufA, n);

    // layer 2: agg on 16-wide, then 16->32 linear with relu, scale
    aggregate_kernel<16, 8><<<gagg, B, 0, stream>>>(bufA, row_start, csr_src, dinv, bufB, n);
    linear_kernel<16, 16, 32, true, true><<<gn, B, 0, stream>>>(bufB, W2, b2, dinv, bufC, n);

    // layer 3: agg on 32-wide, then 32->64 linear, no relu, no scale
    aggregate_kernel<32, 8><<<gagg, B, 0, stream>>>(bufC, row_start, csr_src, dinv, bufD, n);
    linear_kernel<32, 32, 64, false, false><<<gn, B, 0, stream>>>(bufD, W3, b3, dinv, out, n);
}

// Round 5
// 311.032 us; speedup vs baseline: 3.3161x; 1.4357x over previous
//
#include <hip/hip_runtime.h>

// ---- bucket-sort CSR parameters (n <= 131072, so src/dst fit in 17 bits) ----
#define NPB_SHIFT 7
#define NPB       128      // nodes per bucket
#define CHUNK     4096     // edges per hist/scatter block (16 per thread)
#define STAGE_CAP 8192     // bucket_build LDS staging (ints); avg bucket ~4092
#define NBKT_MAX  1024     // LDS bin cap (needs nbkt <= 1024)

// ---------------- pass 1: per-block LDS histogram of dst buckets ----------------

__global__ void hist_kernel(const int* __restrict__ dst, int* __restrict__ hist,
                            int E, int HBr, int nbkt) {
    __shared__ int bins[NBKT_MAX];
    int tid = threadIdx.x;
    for (int i = tid; i < nbkt; i += 256) bins[i] = 0;
    __syncthreads();
    int start = blockIdx.x * CHUNK;
    #pragma unroll
    for (int j = 0; j < 16; ++j) {
        int e = start + j * 256 + tid;
        if (e < E) atomicAdd(&bins[dst[e] >> NPB_SHIFT], 1);
    }
    __syncthreads();
    for (int i = tid; i < nbkt; i += 256)
        hist[(size_t)i * HBr + blockIdx.x] = bins[i];
}

// ---------------- 3-phase exclusive scan over hist matrix (in place) ----------------
// scan_block8: 1024 threads x 8 elements = 8192 per block

__global__ void scan_block8_kernel(int* data, int* __restrict__ partial, int len) {
    __shared__ int wtot[16];
    int tid = threadIdx.x, lane = tid & 63, wid = tid >> 6;
    int base = blockIdx.x * 8192 + tid * 8;
    int v[8]; int s = 0;
    #pragma unroll
    for (int j = 0; j < 8; ++j) {
        int i = base + j;
        v[j] = (i < len) ? data[i] : 0;
        s += v[j];
    }
    int inc = s;
    #pragma unroll
    for (int o = 1; o < 64; o <<= 1) { int t = __shfl_up(inc, o); if (lane >= o) inc += t; }
    if (lane == 63) wtot[wid] = inc;
    __syncthreads();
    if (tid == 0) {
        int run = 0;
        #pragma unroll
        for (int w = 0; w < 16; ++w) { int t = wtot[w]; wtot[w] = run; run += t; }
        partial[blockIdx.x] = run;
    }
    __syncthreads();
    int excl = wtot[wid] + inc - s;
    #pragma unroll
    for (int j = 0; j < 8; ++j) {
        int i = base + j;
        if (i < len) data[i] = excl;
        excl += v[j];
    }
}

__global__ void scan_partials_kernel(int* partial, int nb) {
    int t = threadIdx.x;  // 64 threads; nb <= 128
    int i0 = 2 * t, i1 = 2 * t + 1;
    int v0 = (i0 < nb) ? partial[i0] : 0;
    int v1 = (i1 < nb) ? partial[i1] : 0;
    int s = v0 + v1;
    int inc = s;
    #pragma unroll
    for (int o = 1; o < 64; o <<= 1) { int u = __shfl_up(inc, o); if (t >= o) inc += u; }
    int excl = inc - s;
    if (i0 < nb) partial[i0] = excl;
    if (i1 < nb) partial[i1] = excl + v0;
}

__global__ void add_base_kernel(int* data, const int* __restrict__ partial, int len) {
    int i = blockIdx.x * blockDim.x + threadIdx.x;
    if (i < len) data[i] += partial[i >> 13];
}

// ---------------- pass 2: tile-sort scatter into bucket-ordered ebuf ----------------
// payload packed: (dst & 127) << 17 | src   (src < 2^17)

__global__ void scatter_kernel(const int* __restrict__ src, const int* __restrict__ dst,
                               const int* __restrict__ offset, int* __restrict__ ebuf,
                               int E, int HBr, int nbkt) {
    __shared__ int gbase[NBKT_MAX];
    __shared__ int thist[NBKT_MAX];
    __shared__ int toff[NBKT_MAX + 1];
    __shared__ int stage[CHUNK];
    __shared__ unsigned short bstage[CHUNK];
    __shared__ int wtot4[4];
    int tid = threadIdx.x, lane = tid & 63, wid = tid >> 6;
    for (int i = tid; i < nbkt; i += 256) gbase[i] = offset[(size_t)i * HBr + blockIdx.x];
    for (int i = tid; i < NBKT_MAX; i += 256) thist[i] = 0;
    __syncthreads();
    int start = blockIdx.x * CHUNK;
    int s_[16], d_[16], r_[16];
    #pragma unroll
    for (int j = 0; j < 16; ++j) {
        int e = start + j * 256 + tid;
        if (e < E) {
            s_[j] = src[e];
            d_[j] = dst[e];
            r_[j] = atomicAdd(&thist[d_[j] >> NPB_SHIFT], 1);
        } else {
            d_[j] = -1;
        }
    }
    __syncthreads();
    // exclusive scan of thist[0..1023] -> toff (256 threads x 4)
    int a0 = thist[4 * tid], a1 = thist[4 * tid + 1],
        a2 = thist[4 * tid + 2], a3 = thist[4 * tid + 3];
    int ss = a0 + a1 + a2 + a3;
    int inc = ss;
    #pragma unroll
    for (int o = 1; o < 64; o <<= 1) { int t = __shfl_up(inc, o); if (lane >= o) inc += t; }
    if (lane == 63) wtot4[wid] = inc;
    __syncthreads();
    int wbase = 0;
    for (int w = 0; w < wid; ++w) wbase += wtot4[w];
    int excl = wbase + inc - ss;
    toff[4 * tid]     = excl;
    toff[4 * tid + 1] = excl + a0;
    toff[4 * tid + 2] = excl + a0 + a1;
    toff[4 * tid + 3] = excl + a0 + a1 + a2;
    if (tid == 255) toff[1024] = excl + ss;  // total valid
    __syncthreads();
    #pragma unroll
    for (int j = 0; j < 16; ++j) {
        if (d_[j] >= 0) {
            int b = d_[j] >> NPB_SHIFT;
            int q = toff[b] + r_[j];
            stage[q]  = ((d_[j] & (NPB - 1)) << 17) | s_[j];
            bstage[q] = (unsigned short)b;
        }
    }
    __syncthreads();
    int total = toff[1024];
    for (int j = tid; j < total; j += 256) {
        int b = bstage[j];
        ebuf[gbase[b] + (j - toff[b])] = stage[j];
    }
}

// ---------------- pass 3: per-bucket CSR build + row_start + dinv ----------------

__global__ void bucket_build_kernel(const int* __restrict__ ebuf, const int* __restrict__ offset,
                                    int* __restrict__ csr_src, int* __restrict__ row_start,
                                    float* __restrict__ dinv, int E, int HBr, int nbkt, int n) {
    __shared__ int cnt[NPB], cur[NPB];
    __shared__ int stage[STAGE_CAP];
    __shared__ int wtot2[2];
    int tid = threadIdx.x;
    int k = blockIdx.x;
    int bb = offset[(size_t)k * HBr];
    int be = (k + 1 < nbkt) ? offset[(size_t)(k + 1) * HBr] : E;
    int bsize = be - bb;
    if (tid < NPB) cnt[tid] = 0;
    __syncthreads();
    for (int e = bb + tid; e < be; e += 256) atomicAdd(&cnt[ebuf[e] >> 17], 1);
    __syncthreads();
    int lane = tid & 63, wid = tid >> 6;
    int c = 0, inc = 0;
    if (tid < NPB) {  // waves 0,1 entirely inside
        c = cnt[tid];
        inc = c;
        #pragma unroll
        for (int o = 1; o < 64; o <<= 1) { int t = __shfl_up(inc, o); if (lane >= o) inc += t; }
        if (lane == 63) wtot2[wid] = inc;
    }
    __syncthreads();
    if (tid < NPB) {
        int base = (wid == 1) ? wtot2[0] : 0;
        int excl = base + inc - c;
        cur[tid] = excl;
        int node = k * NPB + tid;
        if (node < n) {
            row_start[node] = bb + excl;
            dinv[node] = rsqrtf((float)(c + 1));  // self-loop
        }
    }
    if (k == 0 && tid == 0) row_start[n] = E;
    __syncthreads();
    if (bsize <= STAGE_CAP) {
        for (int e = bb + tid; e < be; e += 256) {
            int v = ebuf[e];
            int r = atomicAdd(&cur[v >> 17], 1);
            stage[r] = v & 0x1FFFF;
        }
        __syncthreads();
        for (int j = tid; j < bsize; j += 256) csr_src[bb + j] = stage[j];  // coalesced
    } else {  // safety fallback (huge bucket)
        for (int e = bb + tid; e < be; e += 256) {
            int v = ebuf[e];
            int r = atomicAdd(&cur[v >> 17], 1);
            csr_src[bb + r] = v & 0x1FFFF;
        }
    }
}

// ---------------- pad + scale: g0[i][k] = (k<11) ? x[i][k]*dinv[i] : 0  (16-wide) ------------

__global__ void pad_scale_kernel(const float* __restrict__ x, const float* __restrict__ dinv,
                                 float* __restrict__ g, int n) {
    int i = blockIdx.x * blockDim.x + threadIdx.x;
    if (i >= n) return;
    float s = dinv[i];
    float v[16];
    #pragma unroll
    for (int k = 0; k < 11; ++k) v[k] = x[i * 11 + k] * s;
    #pragma unroll
    for (int k = 11; k < 16; ++k) v[k] = 0.f;
    #pragma unroll
    for (int k = 0; k < 16; ++k) g[i * 16 + k] = v[k];
}

// ---------------- gather-aggregate (pre-linear features) ----------------
// pre[d] = dinv[d] * (sum_{s in N(d)} g[s] + g[d]);  g already carries dinv[s].

template <int FOUT, int U>
__global__ void aggregate_kernel(const float* __restrict__ g, const int* __restrict__ row_start,
                                 const int* __restrict__ csr_src, const float* __restrict__ dinv,
                                 float* __restrict__ pre, int n) {
    constexpr int NPG = 64 / FOUT;
    int lane = threadIdx.x & 63;
    int wid  = threadIdx.x >> 6;
    int node = blockIdx.x * (blockDim.x >> 6) + wid;
    if (node >= n) return;
    int f   = lane % FOUT;
    int grp = lane / FOUT;
    int beg = row_start[node];
    int end = row_start[node + 1];
    float acc = 0.f;
    int p = beg + grp;
    for (; p + (U - 1) * NPG < end; p += U * NPG) {
        int   s[U];
        float v[U];
        #pragma unroll
        for (int u = 0; u < U; ++u) s[u] = csr_src[p + u * NPG];
        #pragma unroll
        for (int u = 0; u < U; ++u) v[u] = g[(size_t)s[u] * FOUT + f];
        #pragma unroll
        for (int u = 0; u < U; ++u) acc += v[u];
    }
    for (; p < end; p += NPG) acc += g[(size_t)csr_src[p] * FOUT + f];
    #pragma unroll
    for (int off = FOUT; off < 64; off <<= 1) acc += __shfl_xor(acc, off);
    float val = dinv[node] * (acc + g[node * FOUT + f]);
    if (grp == 0) pre[node * FOUT + f] = val;
}

// ---------------- post-agg linear: out = [relu](pre @ W + b) [* dinv] ----------------

template <int FINP, int FINR, int FOUT, bool RELU, bool SCALE>
__global__ void linear_kernel(const float* __restrict__ pre, const float* __restrict__ W,
                              const float* __restrict__ bias, const float* __restrict__ dinv,
                              float* __restrict__ out, int n) {
    __shared__ float sW[FINP * FOUT];
    __shared__ float sB[FOUT];
    for (int i = threadIdx.x; i < FINP * FOUT; i += blockDim.x)
        sW[i] = (i < FINR * FOUT) ? W[i] : 0.f;
    for (int i = threadIdx.x; i < FOUT; i += blockDim.x) sB[i] = bias[i];
    __syncthreads();
    int node = blockIdx.x * blockDim.x + threadIdx.x;
    if (node >= n) return;
    float xi[FINP];
    #pragma unroll
    for (int k = 0; k < FINP; ++k) xi[k] = pre[node * FINP + k];
    float s = SCALE ? dinv[node] : 1.f;
    #pragma unroll
    for (int f = 0; f < FOUT; ++f) {
        float acc = sB[f];
        #pragma unroll
        for (int k = 0; k < FINP; ++k) acc = fmaf(xi[k], sW[k * FOUT + f], acc);
        if (RELU) acc = fmaxf(acc, 0.f);
        out[node * FOUT + f] = acc * s;
    }
}

// ---------------- launch ----------------

extern "C" void kernel_launch(void* const* d_in, const int* in_sizes, int n_in,
                              void* d_out, int out_size, void* d_ws, size_t ws_size,
                              hipStream_t stream) {
    const float* x  = (const float*)d_in[0];
    const int*   ei = (const int*)d_in[1];
    const float* W1 = (const float*)d_in[2];
    const float* b1 = (const float*)d_in[3];
    const float* W2 = (const float*)d_in[4];
    const float* b2 = (const float*)d_in[5];
    const float* W3 = (const float*)d_in[6];
    const float* b3 = (const float*)d_in[7];
    float* out = (float*)d_out;

    const int n = in_sizes[0] / 11;   // 100000
    const int E = in_sizes[1] / 2;    // 3200000
    const int* src = ei;
    const int* dst = ei + E;

    const int nbkt = (n + NPB - 1) >> NPB_SHIFT;        // 782
    const int HBr  = (E + CHUNK - 1) / CHUNK;           // 782
    const size_t len = (size_t)nbkt * HBr;              // 611,524
    const int nb = (int)((len + 8191) / 8192);          // 75 (<=128)

    char* ws = (char*)d_ws;
    size_t off = 0;
    auto alloc = [&](size_t bytes) {
        void* p = ws + off;
        off = (off + bytes + 255) & ~(size_t)255;
        return p;
    };
    int*   offbuf    = (int*)  alloc(len * 4);              // hist -> offsets (in-place scan)
    int*   partial   = (int*)  alloc((size_t)128 * 4);
    int*   ebuf      = (int*)  alloc((size_t)E * 4);        // bucket-ordered packed edges
    int*   csr_src   = (int*)  alloc((size_t)E * 4);
    int*   row_start = (int*)  alloc((size_t)(n + 1) * 4);
    float* dinv      = (float*)alloc((size_t)n * 4);
    float* bufA      = (float*)alloc((size_t)n * 16 * 4);
    float* bufB      = (float*)alloc((size_t)n * 16 * 4);
    float* bufC      = (float*)alloc((size_t)n * 32 * 4);
    float* bufD      = (float*)alloc((size_t)n * 32 * 4);
    (void)ws_size;

    const int B = 256;
    int gn   = (n + B - 1) / B;
    int glen = (int)((len + B - 1) / B);
    int gagg = (n + 3) / 4;           // one wave per node

    // ---- atomic-free CSR build ----
    hist_kernel<<<HBr, B, 0, stream>>>(dst, offbuf, E, HBr, nbkt);
    scan_block8_kernel<<<nb, 1024, 0, stream>>>(offbuf, partial, (int)len);
    scan_partials_kernel<<<1, 64, 0, stream>>>(partial, nb);
    add_base_kernel<<<glen, B, 0, stream>>>(offbuf, partial, (int)len);
    scatter_kernel<<<HBr, B, 0, stream>>>(src, dst, offbuf, ebuf, E, HBr, nbkt);
    bucket_build_kernel<<<nbkt, B, 0, stream>>>(ebuf, offbuf, csr_src, row_start, dinv, E, HBr, nbkt, n);

    // ---- g0 = pad16(x) * dinv ----
    pad_scale_kernel<<<gn, B, 0, stream>>>(x, dinv, bufA, n);

    // layer 1: agg on 16-wide (11 used), then 11->16 linear, relu, scale
    aggregate_kernel<16, 8><<<gagg, B, 0, stream>>>(bufA, row_start, csr_src, dinv, bufB, n);
    linear_kernel<16, 11, 16, true, true><<<gn, B, 0, stream>>>(bufB, W1, b1, dinv, bufA, n);

    // layer 2: agg on 16-wide, then 16->32 linear, relu, scale
    aggregate_kernel<16, 8><<<gagg, B, 0, stream>>>(bufA, row_start, csr_src, dinv, bufB, n);
    linear_kernel<16, 16, 32, true, true><<<gn, B, 0, stream>>>(bufB, W2, b2, dinv, bufC, n);

    // layer 3: agg on 32-wide, then 32->64 linear, no relu, no scale
    aggregate_kernel<32, 8><<<gagg, B, 0, stream>>>(bufC, row_start, csr_src, dinv, bufD, n);
    linear_kernel<32, 32, 64, false, false><<<gn, B, 0, stream>>>(bufD, W3, b3, dinv, out, n);
}

// Round 6
// 298.861 us; speedup vs baseline: 3.4512x; 1.0407x over previous
//
#include <hip/hip_runtime.h>

// ---- bucket-sort CSR parameters (n <= 131072, so src/dst fit in 17 bits) ----
#define NPB_SHIFT 7
#define NPB       128      // nodes per bucket
#define CHUNK     4096     // edges per hist/scatter block (16 per thread)
#define STAGE_CAP 8192     // bucket_build LDS staging (ints); avg bucket ~4092
#define NBKT_MAX  1024     // LDS bin cap (needs nbkt <= 1024)

// ---------------- pass 1: per-block LDS histogram of dst buckets ----------------

__global__ void hist_kernel(const int* __restrict__ dst, int* __restrict__ hist,
                            int E, int HBr, int nbkt) {
    __shared__ int bins[NBKT_MAX];
    int tid = threadIdx.x;
    for (int i = tid; i < nbkt; i += 256) bins[i] = 0;
    __syncthreads();
    int start = blockIdx.x * CHUNK;
    #pragma unroll
    for (int j = 0; j < 16; ++j) {
        int e = start + j * 256 + tid;
        if (e < E) atomicAdd(&bins[dst[e] >> NPB_SHIFT], 1);
    }
    __syncthreads();
    for (int i = tid; i < nbkt; i += 256)
        hist[(size_t)i * HBr + blockIdx.x] = bins[i];
}

// ---------------- 3-phase exclusive scan over hist matrix (in place) ----------------

__global__ void scan_block8_kernel(int* data, int* __restrict__ partial, int len) {
    __shared__ int wtot[16];
    int tid = threadIdx.x, lane = tid & 63, wid = tid >> 6;
    int base = blockIdx.x * 8192 + tid * 8;
    int v[8]; int s = 0;
    #pragma unroll
    for (int j = 0; j < 8; ++j) {
        int i = base + j;
        v[j] = (i < len) ? data[i] : 0;
        s += v[j];
    }
    int inc = s;
    #pragma unroll
    for (int o = 1; o < 64; o <<= 1) { int t = __shfl_up(inc, o); if (lane >= o) inc += t; }
    if (lane == 63) wtot[wid] = inc;
    __syncthreads();
    if (tid == 0) {
        int run = 0;
        #pragma unroll
        for (int w = 0; w < 16; ++w) { int t = wtot[w]; wtot[w] = run; run += t; }
        partial[blockIdx.x] = run;
    }
    __syncthreads();
    int excl = wtot[wid] + inc - s;
    #pragma unroll
    for (int j = 0; j < 8; ++j) {
        int i = base + j;
        if (i < len) data[i] = excl;
        excl += v[j];
    }
}

__global__ void scan_partials_kernel(int* partial, int nb) {
    int t = threadIdx.x;  // 64 threads; nb <= 128
    int i0 = 2 * t, i1 = 2 * t + 1;
    int v0 = (i0 < nb) ? partial[i0] : 0;
    int v1 = (i1 < nb) ? partial[i1] : 0;
    int s = v0 + v1;
    int inc = s;
    #pragma unroll
    for (int o = 1; o < 64; o <<= 1) { int u = __shfl_up(inc, o); if (t >= o) inc += u; }
    int excl = inc - s;
    if (i0 < nb) partial[i0] = excl;
    if (i1 < nb) partial[i1] = excl + v0;
}

__global__ void add_base_kernel(int* data, const int* __restrict__ partial, int len) {
    int i = blockIdx.x * blockDim.x + threadIdx.x;
    if (i < len) data[i] += partial[i >> 13];
}

// ---------------- pass 2: tile-sort scatter into bucket-ordered ebuf ----------------
// payload packed: (dst & 127) << 17 | src   (src < 2^17)

__global__ void scatter_kernel(const int* __restrict__ src, const int* __restrict__ dst,
                               const int* __restrict__ offset, int* __restrict__ ebuf,
                               int E, int HBr, int nbkt) {
    __shared__ int gbase[NBKT_MAX];
    __shared__ int thist[NBKT_MAX];
    __shared__ int toff[NBKT_MAX + 1];
    __shared__ int stage[CHUNK];
    __shared__ unsigned short bstage[CHUNK];
    __shared__ int wtot4[4];
    int tid = threadIdx.x, lane = tid & 63, wid = tid >> 6;
    for (int i = tid; i < nbkt; i += 256) gbase[i] = offset[(size_t)i * HBr + blockIdx.x];
    for (int i = tid; i < NBKT_MAX; i += 256) thist[i] = 0;
    __syncthreads();
    int start = blockIdx.x * CHUNK;
    int s_[16], d_[16], r_[16];
    #pragma unroll
    for (int j = 0; j < 16; ++j) {
        int e = start + j * 256 + tid;
        if (e < E) {
            s_[j] = src[e];
            d_[j] = dst[e];
            r_[j] = atomicAdd(&thist[d_[j] >> NPB_SHIFT], 1);
        } else {
            d_[j] = -1;
        }
    }
    __syncthreads();
    int a0 = thist[4 * tid], a1 = thist[4 * tid + 1],
        a2 = thist[4 * tid + 2], a3 = thist[4 * tid + 3];
    int ss = a0 + a1 + a2 + a3;
    int inc = ss;
    #pragma unroll
    for (int o = 1; o < 64; o <<= 1) { int t = __shfl_up(inc, o); if (lane >= o) inc += t; }
    if (lane == 63) wtot4[wid] = inc;
    __syncthreads();
    int wbase = 0;
    for (int w = 0; w < wid; ++w) wbase += wtot4[w];
    int excl = wbase + inc - ss;
    toff[4 * tid]     = excl;
    toff[4 * tid + 1] = excl + a0;
    toff[4 * tid + 2] = excl + a0 + a1;
    toff[4 * tid + 3] = excl + a0 + a1 + a2;
    if (tid == 255) toff[1024] = excl + ss;  // total valid
    __syncthreads();
    #pragma unroll
    for (int j = 0; j < 16; ++j) {
        if (d_[j] >= 0) {
            int b = d_[j] >> NPB_SHIFT;
            int q = toff[b] + r_[j];
            stage[q]  = ((d_[j] & (NPB - 1)) << 17) | s_[j];
            bstage[q] = (unsigned short)b;
        }
    }
    __syncthreads();
    int total = toff[1024];
    for (int j = tid; j < total; j += 256) {
        int b = bstage[j];
        ebuf[gbase[b] + (j - toff[b])] = stage[j];
    }
}

// ---------------- pass 3: per-bucket CSR build + row_start + dinv ----------------

__global__ void bucket_build_kernel(const int* __restrict__ ebuf, const int* __restrict__ offset,
                                    int* __restrict__ csr_src, int* __restrict__ row_start,
                                    float* __restrict__ dinv, int E, int HBr, int nbkt, int n) {
    __shared__ int cnt[NPB], cur[NPB];
    __shared__ int stage[STAGE_CAP];
    __shared__ int wtot2[2];
    int tid = threadIdx.x;
    int k = blockIdx.x;
    int bb = offset[(size_t)k * HBr];
    int be = (k + 1 < nbkt) ? offset[(size_t)(k + 1) * HBr] : E;
    int bsize = be - bb;
    if (tid < NPB) cnt[tid] = 0;
    __syncthreads();
    for (int e = bb + tid; e < be; e += 256) atomicAdd(&cnt[ebuf[e] >> 17], 1);
    __syncthreads();
    int lane = tid & 63, wid = tid >> 6;
    int c = 0, inc = 0;
    if (tid < NPB) {
        c = cnt[tid];
        inc = c;
        #pragma unroll
        for (int o = 1; o < 64; o <<= 1) { int t = __shfl_up(inc, o); if (lane >= o) inc += t; }
        if (lane == 63) wtot2[wid] = inc;
    }
    __syncthreads();
    if (tid < NPB) {
        int base = (wid == 1) ? wtot2[0] : 0;
        int excl = base + inc - c;
        cur[tid] = excl;
        int node = k * NPB + tid;
        if (node < n) {
            row_start[node] = bb + excl;
            dinv[node] = rsqrtf((float)(c + 1));  // self-loop
        }
    }
    if (k == 0 && tid == 0) row_start[n] = E;
    __syncthreads();
    if (bsize <= STAGE_CAP) {
        for (int e = bb + tid; e < be; e += 256) {
            int v = ebuf[e];
            int r = atomicAdd(&cur[v >> 17], 1);
            stage[r] = v & 0x1FFFF;
        }
        __syncthreads();
        for (int j = tid; j < bsize; j += 256) csr_src[bb + j] = stage[j];  // coalesced
    } else {
        for (int e = bb + tid; e < be; e += 256) {
            int v = ebuf[e];
            int r = atomicAdd(&cur[v >> 17], 1);
            csr_src[bb + r] = v & 0x1FFFF;
        }
    }
}

// ---------------- pad + scale: g0[i][k] = (k<11) ? x[i][k]*dinv[i] : 0  (16-wide) ------------

__global__ void pad_scale_kernel(const float* __restrict__ x, const float* __restrict__ dinv,
                                 float* __restrict__ g, int n) {
    int i = blockIdx.x * blockDim.x + threadIdx.x;
    if (i >= n) return;
    float s = dinv[i];
    float v[16];
    #pragma unroll
    for (int k = 0; k < 11; ++k) v[k] = x[i * 11 + k] * s;
    #pragma unroll
    for (int k = 11; k < 16; ++k) v[k] = 0.f;
    #pragma unroll
    for (int k = 0; k < 16; ++k) g[i * 16 + k] = v[k];
}

// ---------------- fused gather-aggregate + linear ----------------
// pre = dinv[d] * (sum_{s in N(d)} g[s] + g[d])        (g rows carry dinv[s])
// out[d] = [relu](pre @ W + b) [* dinv[d]]             (scale preps next layer's g)
// One wave per node. 8 lanes per row (float2 for FIN=16, float4 for FIN=32),
// 8 rows per step, U=4 steps in flight -> 32 rows per main iteration.

template <int FIN, int FINR, int FOUT, bool RELU, bool SCALE>
__global__ void fused_agg_linear_kernel(const float* __restrict__ g,
                                        const int* __restrict__ row_start,
                                        const int* __restrict__ csr_src,
                                        const float* __restrict__ dinv,
                                        const float* __restrict__ W,
                                        const float* __restrict__ bias,
                                        float* __restrict__ out, int n) {
    constexpr int VW  = FIN / 8;   // floats per lane (2 or 4)
    constexpr int NPG = 8;         // rows per step (8 lanes per row)
    constexpr int U   = 4;
    __shared__ float sW[FINR * FOUT];
    __shared__ float sB[FOUT];
    for (int i = threadIdx.x; i < FINR * FOUT; i += blockDim.x) sW[i] = W[i];
    for (int i = threadIdx.x; i < FOUT; i += blockDim.x) sB[i] = bias[i];
    __syncthreads();
    int lane = threadIdx.x & 63;
    int wid  = threadIdx.x >> 6;
    int node = blockIdx.x * (blockDim.x >> 6) + wid;
    if (node >= n) return;
    int q   = lane & 7;        // position within row (vector index)
    int grp = lane >> 3;       // which row of the 8-row batch
    int beg = row_start[node];
    int end = row_start[node + 1];
    float acc[VW];
    #pragma unroll
    for (int c = 0; c < VW; ++c) acc[c] = 0.f;

    int p = beg + grp;
    if constexpr (VW == 2) {
        const float2* g2 = reinterpret_cast<const float2*>(g);
        for (; p + (U - 1) * NPG < end; p += U * NPG) {
            int s[U]; float2 v[U];
            #pragma unroll
            for (int u = 0; u < U; ++u) s[u] = csr_src[p + u * NPG];
            #pragma unroll
            for (int u = 0; u < U; ++u) v[u] = g2[(size_t)s[u] * 8 + q];
            #pragma unroll
            for (int u = 0; u < U; ++u) { acc[0] += v[u].x; acc[1] += v[u].y; }
        }
        for (; p < end; p += NPG) {
            float2 v = g2[(size_t)csr_src[p] * 8 + q];
            acc[0] += v.x; acc[1] += v.y;
        }
    } else {
        const float4* g4 = reinterpret_cast<const float4*>(g);
        for (; p + (U - 1) * NPG < end; p += U * NPG) {
            int s[U]; float4 v[U];
            #pragma unroll
            for (int u = 0; u < U; ++u) s[u] = csr_src[p + u * NPG];
            #pragma unroll
            for (int u = 0; u < U; ++u) v[u] = g4[(size_t)s[u] * 8 + q];
            #pragma unroll
            for (int u = 0; u < U; ++u) {
                acc[0] += v[u].x; acc[1] += v[u].y; acc[2] += v[u].z; acc[3] += v[u].w;
            }
        }
        for (; p < end; p += NPG) {
            float4 v = g4[(size_t)csr_src[p] * 8 + q];
            acc[0] += v.x; acc[1] += v.y; acc[2] += v.z; acc[3] += v.w;
        }
    }

    // butterfly-reduce across the 8 row-groups (all lanes end with column totals)
    #pragma unroll
    for (int off = 8; off < 64; off <<= 1)
        #pragma unroll
        for (int c = 0; c < VW; ++c) acc[c] += __shfl_xor(acc[c], off);

    // add self row, apply dinv[d]
    {
        if constexpr (VW == 2) {
            float2 v = reinterpret_cast<const float2*>(g)[(size_t)node * 8 + q];
            acc[0] += v.x; acc[1] += v.y;
        } else {
            float4 v = reinterpret_cast<const float4*>(g)[(size_t)node * 8 + q];
            acc[0] += v.x; acc[1] += v.y; acc[2] += v.z; acc[3] += v.w;
        }
        float dn = dinv[node];
        #pragma unroll
        for (int c = 0; c < VW; ++c) acc[c] *= dn;
    }

    // in-wave linear: lane computes output feature j = lane % FOUT
    int j = lane % FOUT;
    float o = sB[j];
    #pragma unroll
    for (int f = 0; f < FINR; ++f) {
        float a = __shfl(acc[f % VW], f / VW);  // feature f lives in lane f/VW, comp f%VW
        o = fmaf(a, sW[f * FOUT + j], o);
    }
    if (RELU) o = fmaxf(o, 0.f);
    if (SCALE) o *= dinv[node];
    if (lane < FOUT) out[(size_t)node * FOUT + j] = o;
}

// ---------------- launch ----------------

extern "C" void kernel_launch(void* const* d_in, const int* in_sizes, int n_in,
                              void* d_out, int out_size, void* d_ws, size_t ws_size,
                              hipStream_t stream) {
    const float* x  = (const float*)d_in[0];
    const int*   ei = (const int*)d_in[1];
    const float* W1 = (const float*)d_in[2];
    const float* b1 = (const float*)d_in[3];
    const float* W2 = (const float*)d_in[4];
    const float* b2 = (const float*)d_in[5];
    const float* W3 = (const float*)d_in[6];
    const float* b3 = (const float*)d_in[7];
    float* out = (float*)d_out;

    const int n = in_sizes[0] / 11;   // 100000
    const int E = in_sizes[1] / 2;    // 3200000
    const int* src = ei;
    const int* dst = ei + E;

    const int nbkt = (n + NPB - 1) >> NPB_SHIFT;        // 782
    const int HBr  = (E + CHUNK - 1) / CHUNK;           // 782
    const size_t len = (size_t)nbkt * HBr;              // 611,524
    const int nb = (int)((len + 8191) / 8192);          // 75 (<=128)

    char* ws = (char*)d_ws;
    size_t off = 0;
    auto alloc = [&](size_t bytes) {
        void* p = ws + off;
        off = (off + bytes + 255) & ~(size_t)255;
        return p;
    };
    int*   offbuf    = (int*)  alloc(len * 4);
    int*   partial   = (int*)  alloc((size_t)128 * 4);
    int*   ebuf      = (int*)  alloc((size_t)E * 4);
    int*   csr_src   = (int*)  alloc((size_t)E * 4);
    int*   row_start = (int*)  alloc((size_t)(n + 1) * 4);
    float* dinv      = (float*)alloc((size_t)n * 4);
    float* g0        = (float*)alloc((size_t)n * 16 * 4);
    float* g1        = (float*)alloc((size_t)n * 16 * 4);
    float* g2        = (float*)alloc((size_t)n * 32 * 4);
    (void)ws_size;

    const int B = 256;
    int gn   = (n + B - 1) / B;
    int glen = (int)((len + B - 1) / B);
    int gagg = (n + 3) / 4;           // one wave per node

    // ---- atomic-free CSR build ----
    hist_kernel<<<HBr, B, 0, stream>>>(dst, offbuf, E, HBr, nbkt);
    scan_block8_kernel<<<nb, 1024, 0, stream>>>(offbuf, partial, (int)len);
    scan_partials_kernel<<<1, 64, 0, stream>>>(partial, nb);
    add_base_kernel<<<glen, B, 0, stream>>>(offbuf, partial, (int)len);
    scatter_kernel<<<HBr, B, 0, stream>>>(src, dst, offbuf, ebuf, E, HBr, nbkt);
    bucket_build_kernel<<<nbkt, B, 0, stream>>>(ebuf, offbuf, csr_src, row_start, dinv, E, HBr, nbkt, n);

    // ---- g0 = pad16(x) * dinv ----
    pad_scale_kernel<<<gn, B, 0, stream>>>(x, dinv, g0, n);

    // layer 1: agg(16-wide, 11 real) + 11->16 linear + relu, scaled for next layer
    fused_agg_linear_kernel<16, 11, 16, true, true>
        <<<gagg, B, 0, stream>>>(g0, row_start, csr_src, dinv, W1, b1, g1, n);

    // layer 2: agg(16) + 16->32 linear + relu, scaled
    fused_agg_linear_kernel<16, 16, 32, true, true>
        <<<gagg, B, 0, stream>>>(g1, row_start, csr_src, dinv, W2, b2, g2, n);

    // layer 3: agg(32) + 32->64 linear + bias, no relu, no scale
    fused_agg_linear_kernel<32, 32, 64, false, false>
        <<<gagg, B, 0, stream>>>(g2, row_start, csr_src, dinv, W3, b3, out, n);
}

// Round 7
// 295.537 us; speedup vs baseline: 3.4900x; 1.0112x over previous
//
#include <hip/hip_runtime.h>

// ---- bucket-sort CSR parameters (n <= 131072, so src/dst fit in 17 bits) ----
#define NPB_SHIFT 7
#define NPB       128      // nodes per bucket
#define CHUNK     4096     // edges per hist/scatter block (16 per thread)
#define STAGE_CAP 8192     // bucket_build LDS staging (ints); avg bucket ~4092
#define NBKT_MAX  1024     // LDS bin cap (needs nbkt <= 1024)

// ---------------- pass 1: per-block LDS histogram of dst buckets ----------------

__global__ void hist_kernel(const int* __restrict__ dst, int* __restrict__ hist,
                            int E, int HBr, int nbkt) {
    __shared__ int bins[NBKT_MAX];
    int tid = threadIdx.x;
    for (int i = tid; i < nbkt; i += 256) bins[i] = 0;
    __syncthreads();
    int start = blockIdx.x * CHUNK;
    #pragma unroll
    for (int j = 0; j < 16; ++j) {
        int e = start + j * 256 + tid;
        if (e < E) atomicAdd(&bins[dst[e] >> NPB_SHIFT], 1);
    }
    __syncthreads();
    for (int i = tid; i < nbkt; i += 256)
        hist[(size_t)i * HBr + blockIdx.x] = bins[i];
}

// ---------------- 3-phase exclusive scan over hist matrix (in place) ----------------

__global__ void scan_block8_kernel(int* data, int* __restrict__ partial, int len) {
    __shared__ int wtot[16];
    int tid = threadIdx.x, lane = tid & 63, wid = tid >> 6;
    int base = blockIdx.x * 8192 + tid * 8;
    int v[8]; int s = 0;
    #pragma unroll
    for (int j = 0; j < 8; ++j) {
        int i = base + j;
        v[j] = (i < len) ? data[i] : 0;
        s += v[j];
    }
    int inc = s;
    #pragma unroll
    for (int o = 1; o < 64; o <<= 1) { int t = __shfl_up(inc, o); if (lane >= o) inc += t; }
    if (lane == 63) wtot[wid] = inc;
    __syncthreads();
    if (tid == 0) {
        int run = 0;
        #pragma unroll
        for (int w = 0; w < 16; ++w) { int t = wtot[w]; wtot[w] = run; run += t; }
        partial[blockIdx.x] = run;
    }
    __syncthreads();
    int excl = wtot[wid] + inc - s;
    #pragma unroll
    for (int j = 0; j < 8; ++j) {
        int i = base + j;
        if (i < len) data[i] = excl;
        excl += v[j];
    }
}

__global__ void scan_partials_kernel(int* partial, int nb) {
    int t = threadIdx.x;  // 64 threads; nb <= 128
    int i0 = 2 * t, i1 = 2 * t + 1;
    int v0 = (i0 < nb) ? partial[i0] : 0;
    int v1 = (i1 < nb) ? partial[i1] : 0;
    int s = v0 + v1;
    int inc = s;
    #pragma unroll
    for (int o = 1; o < 64; o <<= 1) { int u = __shfl_up(inc, o); if (t >= o) inc += u; }
    int excl = inc - s;
    if (i0 < nb) partial[i0] = excl;
    if (i1 < nb) partial[i1] = excl + v0;
}

__global__ void add_base_kernel(int* data, const int* __restrict__ partial, int len) {
    int i = blockIdx.x * blockDim.x + threadIdx.x;
    if (i < len) data[i] += partial[i >> 13];
}

// ---------------- pass 2: tile-sort scatter into bucket-ordered ebuf ----------------
// payload packed: (dst & 127) << 17 | src   (src < 2^17)

__global__ void scatter_kernel(const int* __restrict__ src, const int* __restrict__ dst,
                               const int* __restrict__ offset, int* __restrict__ ebuf,
                               int E, int HBr, int nbkt) {
    __shared__ int gbase[NBKT_MAX];
    __shared__ int thist[NBKT_MAX];
    __shared__ int toff[NBKT_MAX + 1];
    __shared__ int stage[CHUNK];
    __shared__ unsigned short bstage[CHUNK];
    __shared__ int wtot4[4];
    int tid = threadIdx.x, lane = tid & 63, wid = tid >> 6;
    for (int i = tid; i < nbkt; i += 256) gbase[i] = offset[(size_t)i * HBr + blockIdx.x];
    for (int i = tid; i < NBKT_MAX; i += 256) thist[i] = 0;
    __syncthreads();
    int start = blockIdx.x * CHUNK;
    int s_[16], d_[16], r_[16];
    #pragma unroll
    for (int j = 0; j < 16; ++j) {
        int e = start + j * 256 + tid;
        if (e < E) {
            s_[j] = src[e];
            d_[j] = dst[e];
            r_[j] = atomicAdd(&thist[d_[j] >> NPB_SHIFT], 1);
        } else {
            d_[j] = -1;
        }
    }
    __syncthreads();
    int a0 = thist[4 * tid], a1 = thist[4 * tid + 1],
        a2 = thist[4 * tid + 2], a3 = thist[4 * tid + 3];
    int ss = a0 + a1 + a2 + a3;
    int inc = ss;
    #pragma unroll
    for (int o = 1; o < 64; o <<= 1) { int t = __shfl_up(inc, o); if (lane >= o) inc += t; }
    if (lane == 63) wtot4[wid] = inc;
    __syncthreads();
    int wbase = 0;
    for (int w = 0; w < wid; ++w) wbase += wtot4[w];
    int excl = wbase + inc - ss;
    toff[4 * tid]     = excl;
    toff[4 * tid + 1] = excl + a0;
    toff[4 * tid + 2] = excl + a0 + a1;
    toff[4 * tid + 3] = excl + a0 + a1 + a2;
    if (tid == 255) toff[1024] = excl + ss;  // total valid
    __syncthreads();
    #pragma unroll
    for (int j = 0; j < 16; ++j) {
        if (d_[j] >= 0) {
            int b = d_[j] >> NPB_SHIFT;
            int q = toff[b] + r_[j];
            stage[q]  = ((d_[j] & (NPB - 1)) << 17) | s_[j];
            bstage[q] = (unsigned short)b;
        }
    }
    __syncthreads();
    int total = toff[1024];
    for (int j = tid; j < total; j += 256) {
        int b = bstage[j];
        ebuf[gbase[b] + (j - toff[b])] = stage[j];
    }
}

// ---------------- pass 3: per-bucket CSR build + row_start + dinv ----------------

__global__ void bucket_build_kernel(const int* __restrict__ ebuf, const int* __restrict__ offset,
                                    int* __restrict__ csr_src, int* __restrict__ row_start,
                                    float* __restrict__ dinv, int E, int HBr, int nbkt, int n) {
    __shared__ int cnt[NPB], cur[NPB];
    __shared__ int stage[STAGE_CAP];
    __shared__ int wtot2[2];
    int tid = threadIdx.x;
    int k = blockIdx.x;
    int bb = offset[(size_t)k * HBr];
    int be = (k + 1 < nbkt) ? offset[(size_t)(k + 1) * HBr] : E;
    int bsize = be - bb;
    if (tid < NPB) cnt[tid] = 0;
    __syncthreads();
    for (int e = bb + tid; e < be; e += 256) atomicAdd(&cnt[ebuf[e] >> 17], 1);
    __syncthreads();
    int lane = tid & 63, wid = tid >> 6;
    int c = 0, inc = 0;
    if (tid < NPB) {
        c = cnt[tid];
        inc = c;
        #pragma unroll
        for (int o = 1; o < 64; o <<= 1) { int t = __shfl_up(inc, o); if (lane >= o) inc += t; }
        if (lane == 63) wtot2[wid] = inc;
    }
    __syncthreads();
    if (tid < NPB) {
        int base = (wid == 1) ? wtot2[0] : 0;
        int excl = base + inc - c;
        cur[tid] = excl;
        int node = k * NPB + tid;
        if (node < n) {
            row_start[node] = bb + excl;
            dinv[node] = rsqrtf((float)(c + 1));  // self-loop
        }
    }
    if (k == 0 && tid == 0) row_start[n] = E;
    __syncthreads();
    if (bsize <= STAGE_CAP) {
        for (int e = bb + tid; e < be; e += 256) {
            int v = ebuf[e];
            int r = atomicAdd(&cur[v >> 17], 1);
            stage[r] = v & 0x1FFFF;
        }
        __syncthreads();
        for (int j = tid; j < bsize; j += 256) csr_src[bb + j] = stage[j];  // coalesced
    } else {
        for (int e = bb + tid; e < be; e += 256) {
            int v = ebuf[e];
            int r = atomicAdd(&cur[v >> 17], 1);
            csr_src[bb + r] = v & 0x1FFFF;
        }
    }
}

// ---------------- pad + scale: g0[i][k] = (k<11) ? x[i][k]*dinv[i] : 0  (16-wide) ------------

__global__ void pad_scale_kernel(const float* __restrict__ x, const float* __restrict__ dinv,
                                 float* __restrict__ g, int n) {
    int i = blockIdx.x * blockDim.x + threadIdx.x;
    if (i >= n) return;
    float s = dinv[i];
    float v[16];
    #pragma unroll
    for (int k = 0; k < 11; ++k) v[k] = x[i * 11 + k] * s;
    #pragma unroll
    for (int k = 11; k < 16; ++k) v[k] = 0.f;
    #pragma unroll
    for (int k = 0; k < 16; ++k) g[i * 16 + k] = v[k];
}

// ---------------- fused gather-aggregate + linear ----------------
// pre = dinv[d] * (sum_{s in N(d)} g[s] + g[d])        (g rows carry dinv[s])
// out[d] = [relu](pre @ W + b) [* dinv[d]]             (scale preps next layer's g)
// One wave per node, 8 lanes per row. Per 64-row block: one coalesced index load
// (csr_src[p+lane], distributed by shuffle) + 8 predicated row-gather batches with
// clamped addresses -> up to 9 independent requests in flight per lane, no serial tail.

template <int FIN, int FINR, int FOUT, bool RELU, bool SCALE>
__global__ void fused_agg_linear_kernel(const float* __restrict__ g,
                                        const int* __restrict__ row_start,
                                        const int* __restrict__ csr_src,
                                        const float* __restrict__ dinv,
                                        const float* __restrict__ W,
                                        const float* __restrict__ bias,
                                        float* __restrict__ out, int n) {
    constexpr int VW = FIN / 8;   // floats per lane (2 or 4)
    __shared__ float sW[FINR * FOUT];
    __shared__ float sB[FOUT];
    for (int i = threadIdx.x; i < FINR * FOUT; i += blockDim.x) sW[i] = W[i];
    for (int i = threadIdx.x; i < FOUT; i += blockDim.x) sB[i] = bias[i];
    __syncthreads();
    int lane = threadIdx.x & 63;
    int wid  = threadIdx.x >> 6;
    int node = blockIdx.x * (blockDim.x >> 6) + wid;
    if (node >= n) return;
    int q   = lane & 7;        // position within row (vector index)
    int grp = lane >> 3;       // row slot within each 8-row batch
    int beg = row_start[node];
    int end = row_start[node + 1];
    float acc[VW];
    #pragma unroll
    for (int c = 0; c < VW; ++c) acc[c] = 0.f;

    for (int p = beg; p < end; p += 64) {
        int nrem = end - p;                               // wave-uniform
        int idx  = csr_src[min(p + lane, end - 1)];       // coalesced, always in-bounds
        int   s[8];
        float m[8];
        #pragma unroll
        for (int u = 0; u < 8; ++u) {
            int slot  = u * 8 + grp;
            bool val  = slot < nrem;
            int  raw  = __shfl(idx, slot);
            s[u] = val ? raw : node;                      // clamp to self row (cached)
            m[u] = val ? 1.f : 0.f;
        }
        if constexpr (VW == 2) {
            const float2* gv = reinterpret_cast<const float2*>(g);
            float2 v[8];
            #pragma unroll
            for (int u = 0; u < 8; ++u) v[u] = gv[(size_t)s[u] * 8 + q];
            #pragma unroll
            for (int u = 0; u < 8; ++u) {
                acc[0] = fmaf(m[u], v[u].x, acc[0]);
                acc[1] = fmaf(m[u], v[u].y, acc[1]);
            }
        } else {
            const float4* gv = reinterpret_cast<const float4*>(g);
            float4 v[8];
            #pragma unroll
            for (int u = 0; u < 8; ++u) v[u] = gv[(size_t)s[u] * 8 + q];
            #pragma unroll
            for (int u = 0; u < 8; ++u) {
                acc[0] = fmaf(m[u], v[u].x, acc[0]);
                acc[1] = fmaf(m[u], v[u].y, acc[1]);
                acc[2] = fmaf(m[u], v[u].z, acc[2]);
                acc[3] = fmaf(m[u], v[u].w, acc[3]);
            }
        }
    }

    // butterfly-reduce across the 8 row-groups (lanes sharing q end with column totals)
    #pragma unroll
    for (int off = 8; off < 64; off <<= 1)
        #pragma unroll
        for (int c = 0; c < VW; ++c) acc[c] += __shfl_xor(acc[c], off);

    // add self row, apply dinv[d]
    {
        if constexpr (VW == 2) {
            float2 v = reinterpret_cast<const float2*>(g)[(size_t)node * 8 + q];
            acc[0] += v.x; acc[1] += v.y;
        } else {
            float4 v = reinterpret_cast<const float4*>(g)[(size_t)node * 8 + q];
            acc[0] += v.x; acc[1] += v.y; acc[2] += v.z; acc[3] += v.w;
        }
        float dn = dinv[node];
        #pragma unroll
        for (int c = 0; c < VW; ++c) acc[c] *= dn;
    }

    // in-wave linear: lane computes output feature j = lane % FOUT
    int j = lane % FOUT;
    float o = sB[j];
    #pragma unroll
    for (int f = 0; f < FINR; ++f) {
        float a = __shfl(acc[f % VW], f / VW);  // feature f lives in lane f/VW, comp f%VW
        o = fmaf(a, sW[f * FOUT + j], o);
    }
    if (RELU) o = fmaxf(o, 0.f);
    if (SCALE) o *= dinv[node];
    if (lane < FOUT) out[(size_t)node * FOUT + j] = o;
}

// ---------------- launch ----------------

extern "C" void kernel_launch(void* const* d_in, const int* in_sizes, int n_in,
                              void* d_out, int out_size, void* d_ws, size_t ws_size,
                              hipStream_t stream) {
    const float* x  = (const float*)d_in[0];
    const int*   ei = (const int*)d_in[1];
    const float* W1 = (const float*)d_in[2];
    const float* b1 = (const float*)d_in[3];
    const float* W2 = (const float*)d_in[4];
    const float* b2 = (const float*)d_in[5];
    const float* W3 = (const float*)d_in[6];
    const float* b3 = (const float*)d_in[7];
    float* out = (float*)d_out;

    const int n = in_sizes[0] / 11;   // 100000
    const int E = in_sizes[1] / 2;    // 3200000
    const int* src = ei;
    const int* dst = ei + E;

    const int nbkt = (n + NPB - 1) >> NPB_SHIFT;        // 782
    const int HBr  = (E + CHUNK - 1) / CHUNK;           // 782
    const size_t len = (size_t)nbkt * HBr;              // 611,524
    const int nb = (int)((len + 8191) / 8192);          // 75 (<=128)

    char* ws = (char*)d_ws;
    size_t off = 0;
    auto alloc = [&](size_t bytes) {
        void* p = ws + off;
        off = (off + bytes + 255) & ~(size_t)255;
        return p;
    };
    int*   offbuf    = (int*)  alloc(len * 4);
    int*   partial   = (int*)  alloc((size_t)128 * 4);
    int*   ebuf      = (int*)  alloc((size_t)E * 4);
    int*   csr_src   = (int*)  alloc((size_t)E * 4);
    int*   row_start = (int*)  alloc((size_t)(n + 1) * 4);
    float* dinv      = (float*)alloc((size_t)n * 4);
    float* g0        = (float*)alloc((size_t)n * 16 * 4);
    float* g1        = (float*)alloc((size_t)n * 16 * 4);
    float* g2        = (float*)alloc((size_t)n * 32 * 4);
    (void)ws_size;

    const int B = 256;
    int gn   = (n + B - 1) / B;
    int glen = (int)((len + B - 1) / B);
    int gagg = (n + 3) / 4;           // one wave per node

    // ---- atomic-free CSR build ----
    hist_kernel<<<HBr, B, 0, stream>>>(dst, offbuf, E, HBr, nbkt);
    scan_block8_kernel<<<nb, 1024, 0, stream>>>(offbuf, partial, (int)len);
    scan_partials_kernel<<<1, 64, 0, stream>>>(partial, nb);
    add_base_kernel<<<glen, B, 0, stream>>>(offbuf, partial, (int)len);
    scatter_kernel<<<HBr, B, 0, stream>>>(src, dst, offbuf, ebuf, E, HBr, nbkt);
    bucket_build_kernel<<<nbkt, B, 0, stream>>>(ebuf, offbuf, csr_src, row_start, dinv, E, HBr, nbkt, n);

    // ---- g0 = pad16(x) * dinv ----
    pad_scale_kernel<<<gn, B, 0, stream>>>(x, dinv, g0, n);

    // layer 1: agg(16-wide, 11 real) + 11->16 linear + relu, scaled for next layer
    fused_agg_linear_kernel<16, 11, 16, true, true>
        <<<gagg, B, 0, stream>>>(g0, row_start, csr_src, dinv, W1, b1, g1, n);

    // layer 2: agg(16) + 16->32 linear + relu, scaled
    fused_agg_linear_kernel<16, 16, 32, true, true>
        <<<gagg, B, 0, stream>>>(g1, row_start, csr_src, dinv, W2, b2, g2, n);

    // layer 3: agg(32) + 32->64 linear + bias, no relu, no scale
    fused_agg_linear_kernel<32, 32, 64, false, false>
        <<<gagg, B, 0, stream>>>(g2, row_start, csr_src, dinv, W3, b3, out, n);
}